// Round 2
// baseline (592.376 us; speedup 1.0000x reference)
//
#include <hip/hip_runtime.h>
#include <math.h>

#define A_TOT   10647
#define BATCH   64
#define NTGT    50
#define NC      80
#define MAXREC  64
#define MAXHIT  512          // unique hit cells per batch <= 50*9 = 450
#define TOT_CELLS (BATCH * A_TOT)
#define DENSE_BLOCKS ((TOT_CELLS + 255) / 256)     // 2662
#define GRID_K2 (DENSE_BLOCKS + BATCH)             // 2726

struct Rec {
    int cell;
    float tx, ty, tw, th, wwh, tconf;
    unsigned c0, c1, c2;     // 80-bit class set
};

// ---------------------------------------------------------------------------
// K1: per-target anchor matching; emits per-batch deduped scatter records
// (last-write-wins, matching numpy fancy assignment) and a deduped list of
// "hit" cells (iou > IGNORE_THR) used to correct the dense conf sum.
// Also zeroes the accumulators (block 0) — no separate memset dispatches.
// ---------------------------------------------------------------------------
__global__ __launch_bounds__(64) void phaseA(const float* __restrict__ tgt,
                                             int* __restrict__ counts,
                                             Rec* __restrict__ recs,
                                             int* __restrict__ hitcnt,
                                             int* __restrict__ hitlist,
                                             double* __restrict__ sums,
                                             int* __restrict__ done) {
    __shared__ int   s_valid[64];
    __shared__ int   s_idx[64];
    __shared__ float s_tx[64], s_ty[64], s_tw[64], s_th[64], s_wwh[64], s_tc[64];
    __shared__ int   s_cls[64];
    __shared__ Rec   s_rec[NTGT];
    __shared__ int   s_cnt;
    __shared__ unsigned s_bm[336];      // 10647-bit hit bitmap
    __shared__ int   s_hits[MAXHIT];
    __shared__ int   s_hc;

    const int b = blockIdx.x;
    const int n = threadIdx.x;

    if (b == 0 && n == 0) {             // zero global accumulators for this call
        sums[0] = 0.0; sums[1] = 0.0; sums[2] = 0.0;
        *done = 0;
    }

    for (int i = n; i < 336; i += 64) s_bm[i] = 0u;
    if (n == 0) s_hc = 0;
    __syncthreads();

    const float fs[3] = {13.f, 26.f, 52.f};
    const int   ln[3] = {0, 507, 2535};
    const float aw[3][3] = {{3.625f, 4.875f, 11.65625f},
                            {1.875f, 3.875f, 3.6875f},
                            {1.25f,  2.0f,   4.125f}};
    const float ah[3][3] = {{2.8125f, 6.1875f, 10.1875f},
                            {3.8125f, 2.8125f, 7.4375f},
                            {1.625f,  3.75f,   2.875f}};

    int valid = 0;
    if (n < NTGT) {
        const float* t = tgt + (size_t)(b * NTGT + n) * 5;
        float t0 = t[0], t1 = t[1], t2 = t[2], t3 = t[3], t4 = t[4];
        valid = ((t0 + t1 + t2 + t3 + t4) != 0.0f);
        if (valid) {
            float best_m_iou = -1.f;
            int bf = 0, best_a = 0, gi_b = 0, gj_b = 0;
            for (int m = 0; m < 3; m++) {
                float gw = t3 * fs[m], gh = t4 * fs[m];
                int gi = (int)floorf(t1 * fs[m]);
                int gj = (int)floorf(t2 * fs[m]);
                float bi = -1.f; int bk = 0;
                for (int k = 0; k < 3; k++) {
                    float in_ = fminf(gw, aw[m][k]) * fminf(gh, ah[m][k]);
                    float un  = gw * gh + aw[m][k] * ah[m][k] - in_;
                    float iou = in_ / (un + 1e-16f);
                    if (iou > bi) { bi = iou; bk = k; }
                    if (iou > 0.5f) {                         // IGNORE_THR hit
                        int cell = ln[m] + 3 * gi * gj + k;
                        unsigned bit = 1u << (cell & 31);
                        unsigned old = atomicOr(&s_bm[cell >> 5], bit);
                        if (!(old & bit)) {
                            int pos = atomicAdd(&s_hc, 1);
                            s_hits[pos] = cell;
                        }
                    }
                }
                if (bi > best_m_iou) { best_m_iou = bi; bf = m; best_a = bk; gi_b = gi; gj_b = gj; }
            }
            s_idx[n] = ln[bf] + 3 * gi_b * gj_b + best_a;
            s_tx[n]  = t1 * 416.f;
            s_ty[n]  = t2 * 416.f;
            s_tw[n]  = t3 * 416.f;
            s_th[n]  = t4 * 416.f;
            s_wwh[n] = 2.0f - t3 * t4;
            s_tc[n]  = best_m_iou;
            s_cls[n] = (int)t0;
        }
    }
    s_valid[n] = valid;
    __syncthreads();

    if (n == 0) {
        int cnt = 0;
        for (int i = 0; i < NTGT; i++) {
            if (!s_valid[i]) continue;
            int cell = s_idx[i];
            int j = -1;
            for (int q = 0; q < cnt; q++)
                if (s_rec[q].cell == cell) { j = q; break; }
            if (j < 0) {
                j = cnt++;
                s_rec[j].cell = cell;
                s_rec[j].c0 = 0u; s_rec[j].c1 = 0u; s_rec[j].c2 = 0u;
            }
            s_rec[j].tx = s_tx[i];  s_rec[j].ty = s_ty[i];
            s_rec[j].tw = s_tw[i];  s_rec[j].th = s_th[i];
            s_rec[j].wwh = s_wwh[i]; s_rec[j].tconf = s_tc[i];
            int c = s_cls[i];
            if (c < 32)       s_rec[j].c0 |= 1u << c;
            else if (c < 64)  s_rec[j].c1 |= 1u << (c - 32);
            else              s_rec[j].c2 |= 1u << (c - 64);
        }
        s_cnt = cnt;
        counts[b] = cnt;
        hitcnt[b] = s_hc;
    }
    __syncthreads();
    for (int r = n; r < s_cnt; r += 64)
        recs[b * MAXREC + r] = s_rec[r];
    for (int i = n; i < s_hc; i += 64)
        hitlist[b * MAXHIT + i] = s_hits[i];
}

// ---------------------------------------------------------------------------
// K2 (fused): blocks [0, DENSE_BLOCKS) sum -log(1-conf) over ALL cells
// (branchless); blocks [DENSE_BLOCKS, +BATCH) cancel the hit-cell
// contributions (+log(1-conf)) and compute the per-record terms. The last
// block to finish (device-scope ticket) combines everything into d_out.
// ---------------------------------------------------------------------------
__global__ __launch_bounds__(256) void fusedSum(const float* __restrict__ pred,
                                                const int* __restrict__ counts,
                                                const Rec* __restrict__ recs,
                                                const int* __restrict__ hitcnt,
                                                const int* __restrict__ hitlist,
                                                double* __restrict__ sums,
                                                int* __restrict__ done,
                                                float* __restrict__ out) {
    const int bid = blockIdx.x;
    const int tid = threadIdx.x;
    double s1 = 0.0;                      // -> sums[1] (noobj conf BCE numerator)
    double sA = 0.0;                      // -> sums[0] (xywh MSE + masked conf BCE)
    double sC = 0.0;                      // -> sums[2] (class BCE)

    if (bid < DENSE_BLOCKS) {
        int id = bid * 256 + tid;
        if (id < TOT_CELLS) {
            float conf = pred[(size_t)id * 85 + 4];
            s1 -= (double)logf(1.0f - conf);
        }
    } else {
        const int b = bid - DENSE_BLOCKS;
        // cancel hit cells (they have noobj == 0 in the reference)
        const int hc = hitcnt[b];
        for (int i = tid; i < hc; i += 256) {
            int cell = hitlist[b * MAXHIT + i];
            float conf = pred[((size_t)b * A_TOT + cell) * 85 + 4];
            s1 += (double)logf(1.0f - conf);
        }
        // per-record terms
        const int cnt = counts[b];
        for (int r = tid; r < cnt; r += 256) {
            Rec rec = recs[b * MAXREC + r];
            const float* p = pred + ((size_t)b * A_TOT + rec.cell) * 85;
            float x = p[0], y = p[1], w = p[2], h = p[3], conf = p[4];
            float wwh = rec.wwh;
            float dx = x * wwh - rec.tx * wwh;
            float dy = y * wwh - rec.ty * wwh;
            float dw = w * wwh - rec.tw * wwh;
            float dh = h * wwh - rec.th * wwh;
            sA += (double)(dx * dx) + (double)(dy * dy) +
                  (double)(dw * dw) + (double)(dh * dh);
            float t = rec.tconf;
            sA -= (double)(t * logf(conf) + (1.0f - t) * logf(1.0f - conf));
        }
        for (int q = tid; q < cnt * NC; q += 256) {
            int r = q / NC, c = q - r * NC;
            Rec rec = recs[b * MAXREC + r];
            float pc = pred[((size_t)b * A_TOT + rec.cell) * 85 + 5 + c];
            unsigned bit;
            if (c < 32)       bit = (rec.c0 >> c) & 1u;
            else if (c < 64)  bit = (rec.c1 >> (c - 32)) & 1u;
            else              bit = (rec.c2 >> (c - 64)) & 1u;
            sC -= bit ? (double)logf(pc) : (double)logf(1.0f - pc);
        }
    }

    // block reduction (wave64 shuffle + LDS across 4 waves)
    for (int off = 32; off; off >>= 1) {
        s1 += __shfl_down(s1, off, 64);
        sA += __shfl_down(sA, off, 64);
        sC += __shfl_down(sC, off, 64);
    }
    __shared__ double w1[4], wA[4], wC[4];
    int lane = tid & 63, w = tid >> 6;
    if (lane == 0) { w1[w] = s1; wA[w] = sA; wC[w] = sC; }
    __syncthreads();
    if (tid == 0) {
        double t1 = w1[0] + w1[1] + w1[2] + w1[3];
        double tA = wA[0] + wA[1] + wA[2] + wA[3];
        double tC = wC[0] + wC[1] + wC[2] + wC[3];
        if (t1 != 0.0) atomicAdd(&sums[1], t1);
        if (tA != 0.0) atomicAdd(&sums[0], tA);
        if (tC != 0.0) atomicAdd(&sums[2], tC);
    }

    // last-block-done combine
    __threadfence();
    __shared__ int s_last;
    if (tid == 0) {
        int t = atomicAdd(done, 1);
        s_last = (t == GRID_K2 - 1) ? 1 : 0;
    }
    __syncthreads();
    if (s_last && tid == 0) {
        double f0 = atomicAdd(&sums[0], 0.0);   // device-scope coherent reads
        double f1 = atomicAdd(&sums[1], 0.0);
        double f2 = atomicAdd(&sums[2], 0.0);
        int npos = 0;
        for (int i = 0; i < BATCH; i++) npos += counts[i];
        double total = (f0 + 0.5 * f1) / (double)TOT_CELLS;
        if (npos > 0) total += f2 / ((double)npos * (double)NC);
        out[0] = (float)total;
    }
}

extern "C" void kernel_launch(void* const* d_in, const int* in_sizes, int n_in,
                              void* d_out, int out_size, void* d_ws, size_t ws_size,
                              hipStream_t stream) {
    const float* pred = (const float*)d_in[0];   // (64, 10647, 85) f32
    const float* tgt  = (const float*)d_in[1];   // (64, 50, 5) f32
    // d_in[2] = stride (always 32; fsizes/last_num hardcoded)

    char* ws = (char*)d_ws;
    double* sums    = (double*)ws;                        // 4 doubles
    int*    done    = (int*)(ws + 32);                    // ticket counter
    int*    counts  = (int*)(ws + 64);                    // 64 ints
    int*    hitcnt  = (int*)(ws + 320);                   // 64 ints
    int*    hitlist = (int*)(ws + 576);                   // 64*512 ints = 128 KiB
    Rec*    recs    = (Rec*)(ws + 576 + 131072);          // 64*64*40 = 160 KiB

    phaseA<<<BATCH, 64, 0, stream>>>(tgt, counts, recs, hitcnt, hitlist, sums, done);
    fusedSum<<<GRID_K2, 256, 0, stream>>>(pred, counts, recs, hitcnt, hitlist,
                                          sums, done, (float*)d_out);
}

// Round 3
// 352.333 us; speedup vs baseline: 1.6813x; 1.6813x over previous
//
#include <hip/hip_runtime.h>
#include <math.h>

#define A_TOT   10647
#define BATCH   64
#define NTGT    50
#define NC      80
#define MAXREC  64
#define MAXHIT  512
#define TOT_CELLS (BATCH * A_TOT)          // 681408
#define NB4     666                        // ceil(681408 / 1024) dense blocks
#define CHUNK   1024                       // cells per dense block (4 per thread)

struct Rec {
    int cell;
    float tx, ty, tw, th, wwh, tconf;
    unsigned c0, c1, c2;     // 80-bit class set
};

// ---------------------------------------------------------------------------
// K1: per-target anchor matching; deduped scatter records (last-write-wins)
// and deduped hit-cell list per batch. Block 0 zeroes the accumulators.
// ---------------------------------------------------------------------------
__global__ __launch_bounds__(64) void phaseA(const float* __restrict__ tgt,
                                             int* __restrict__ counts,
                                             Rec* __restrict__ recs,
                                             int* __restrict__ hitcnt,
                                             int* __restrict__ hitlist,
                                             double* __restrict__ sums) {
    __shared__ int   s_valid[64];
    __shared__ int   s_idx[64];
    __shared__ float s_tx[64], s_ty[64], s_tw[64], s_th[64], s_wwh[64], s_tc[64];
    __shared__ int   s_cls[64];
    __shared__ Rec   s_rec[NTGT];
    __shared__ int   s_cnt;
    __shared__ unsigned s_bm[336];      // 10647-bit hit bitmap
    __shared__ int   s_hits[MAXHIT];
    __shared__ int   s_hc;

    const int b = blockIdx.x;
    const int n = threadIdx.x;

    if (b == 0 && n == 0) {             // zero accumulators for this call
        sums[0] = 0.0; sums[1] = 0.0; sums[2] = 0.0;
    }

    for (int i = n; i < 336; i += 64) s_bm[i] = 0u;
    if (n == 0) s_hc = 0;
    __syncthreads();

    const float fs[3] = {13.f, 26.f, 52.f};
    const int   ln[3] = {0, 507, 2535};
    const float aw[3][3] = {{3.625f, 4.875f, 11.65625f},
                            {1.875f, 3.875f, 3.6875f},
                            {1.25f,  2.0f,   4.125f}};
    const float ah[3][3] = {{2.8125f, 6.1875f, 10.1875f},
                            {3.8125f, 2.8125f, 7.4375f},
                            {1.625f,  3.75f,   2.875f}};

    int valid = 0;
    if (n < NTGT) {
        const float* t = tgt + (size_t)(b * NTGT + n) * 5;
        float t0 = t[0], t1 = t[1], t2 = t[2], t3 = t[3], t4 = t[4];
        valid = ((t0 + t1 + t2 + t3 + t4) != 0.0f);
        if (valid) {
            float best_m_iou = -1.f;
            int bf = 0, best_a = 0, gi_b = 0, gj_b = 0;
            for (int m = 0; m < 3; m++) {
                float gw = t3 * fs[m], gh = t4 * fs[m];
                int gi = (int)floorf(t1 * fs[m]);
                int gj = (int)floorf(t2 * fs[m]);
                float bi = -1.f; int bk = 0;
                for (int k = 0; k < 3; k++) {
                    float in_ = fminf(gw, aw[m][k]) * fminf(gh, ah[m][k]);
                    float un  = gw * gh + aw[m][k] * ah[m][k] - in_;
                    float iou = in_ / (un + 1e-16f);
                    if (iou > bi) { bi = iou; bk = k; }
                    if (iou > 0.5f) {                         // IGNORE_THR hit
                        int cell = ln[m] + 3 * gi * gj + k;
                        unsigned bit = 1u << (cell & 31);
                        unsigned old = atomicOr(&s_bm[cell >> 5], bit);
                        if (!(old & bit)) {
                            int pos = atomicAdd(&s_hc, 1);
                            s_hits[pos] = cell;
                        }
                    }
                }
                if (bi > best_m_iou) { best_m_iou = bi; bf = m; best_a = bk; gi_b = gi; gj_b = gj; }
            }
            s_idx[n] = ln[bf] + 3 * gi_b * gj_b + best_a;
            s_tx[n]  = t1 * 416.f;
            s_ty[n]  = t2 * 416.f;
            s_tw[n]  = t3 * 416.f;
            s_th[n]  = t4 * 416.f;
            s_wwh[n] = 2.0f - t3 * t4;
            s_tc[n]  = best_m_iou;
            s_cls[n] = (int)t0;
        }
    }
    s_valid[n] = valid;
    __syncthreads();

    if (n == 0) {
        int cnt = 0;
        for (int i = 0; i < NTGT; i++) {
            if (!s_valid[i]) continue;
            int cell = s_idx[i];
            int j = -1;
            for (int q = 0; q < cnt; q++)
                if (s_rec[q].cell == cell) { j = q; break; }
            if (j < 0) {
                j = cnt++;
                s_rec[j].cell = cell;
                s_rec[j].c0 = 0u; s_rec[j].c1 = 0u; s_rec[j].c2 = 0u;
            }
            s_rec[j].tx = s_tx[i];  s_rec[j].ty = s_ty[i];
            s_rec[j].tw = s_tw[i];  s_rec[j].th = s_th[i];
            s_rec[j].wwh = s_wwh[i]; s_rec[j].tconf = s_tc[i];
            int c = s_cls[i];
            if (c < 32)       s_rec[j].c0 |= 1u << c;
            else if (c < 64)  s_rec[j].c1 |= 1u << (c - 32);
            else              s_rec[j].c2 |= 1u << (c - 64);
        }
        s_cnt = cnt;
        counts[b] = cnt;
        hitcnt[b] = s_hc;
    }
    __syncthreads();
    for (int r = n; r < s_cnt; r += 64)
        recs[b * MAXREC + r] = s_rec[r];
    for (int i = n; i < s_hc; i += 64)
        hitlist[b * MAXHIT + i] = s_hits[i];
}

// ---------------------------------------------------------------------------
// K2: blocks [0,NB4) sum -log(1-conf) over all cells, 4 independent loads
// per thread for ILP. Blocks [NB4, NB4+BATCH) do the sparse per-batch work.
// NO fences, NO tickets — only device-scope atomicAdds.
// ---------------------------------------------------------------------------
__global__ __launch_bounds__(256) void sumK(const float* __restrict__ pred,
                                            const int* __restrict__ counts,
                                            const Rec* __restrict__ recs,
                                            const int* __restrict__ hitcnt,
                                            const int* __restrict__ hitlist,
                                            double* __restrict__ sums) {
    const int bid = blockIdx.x;
    const int tid = threadIdx.x;

    if (bid < NB4) {
        const int base = bid * CHUNK + tid;
        const int i0 = base, i1 = base + 256, i2 = base + 512, i3 = base + 768;
        // guarded independent loads (pad value 0 -> log(1-0)=0, contributes 0)
        float v0 = (i0 < TOT_CELLS) ? pred[(size_t)i0 * 85 + 4] : 0.0f;
        float v1 = (i1 < TOT_CELLS) ? pred[(size_t)i1 * 85 + 4] : 0.0f;
        float v2 = (i2 < TOT_CELLS) ? pred[(size_t)i2 * 85 + 4] : 0.0f;
        float v3 = (i3 < TOT_CELLS) ? pred[(size_t)i3 * 85 + 4] : 0.0f;
        double s = -((double)logf(1.0f - v0) + (double)logf(1.0f - v1) +
                     (double)logf(1.0f - v2) + (double)logf(1.0f - v3));
        for (int off = 32; off; off >>= 1) s += __shfl_down(s, off, 64);
        __shared__ double w_[4];
        int lane = tid & 63, w = tid >> 6;
        if (lane == 0) w_[w] = s;
        __syncthreads();
        if (tid == 0) atomicAdd(&sums[1], w_[0] + w_[1] + w_[2] + w_[3]);
    } else {
        const int b = bid - NB4;
        double s1 = 0.0, sA = 0.0, sC = 0.0;
        // cancel hit cells (noobj==0 in the reference)
        const int hc = hitcnt[b];
        for (int i = tid; i < hc; i += 256) {
            int cell = hitlist[b * MAXHIT + i];
            float conf = pred[((size_t)b * A_TOT + cell) * 85 + 4];
            s1 += (double)logf(1.0f - conf);
        }
        // masked-cell terms: xywh MSE + conf BCE
        const int cnt = counts[b];
        for (int r = tid; r < cnt; r += 256) {
            Rec rec = recs[b * MAXREC + r];
            const float* p = pred + ((size_t)b * A_TOT + rec.cell) * 85;
            float x = p[0], y = p[1], w = p[2], h = p[3], conf = p[4];
            float wwh = rec.wwh;
            float dx = x * wwh - rec.tx * wwh;
            float dy = y * wwh - rec.ty * wwh;
            float dw = w * wwh - rec.tw * wwh;
            float dh = h * wwh - rec.th * wwh;
            sA += (double)(dx * dx) + (double)(dy * dy) +
                  (double)(dw * dw) + (double)(dh * dh);
            float t = rec.tconf;
            sA -= (double)(t * logf(conf) + (1.0f - t) * logf(1.0f - conf));
        }
        // class BCE
        for (int q = tid; q < cnt * NC; q += 256) {
            int r = q / NC, c = q - r * NC;
            Rec rec = recs[b * MAXREC + r];
            float pc = pred[((size_t)b * A_TOT + rec.cell) * 85 + 5 + c];
            unsigned bit;
            if (c < 32)       bit = (rec.c0 >> c) & 1u;
            else if (c < 64)  bit = (rec.c1 >> (c - 32)) & 1u;
            else              bit = (rec.c2 >> (c - 64)) & 1u;
            sC -= bit ? (double)logf(pc) : (double)logf(1.0f - pc);
        }
        for (int off = 32; off; off >>= 1) {
            s1 += __shfl_down(s1, off, 64);
            sA += __shfl_down(sA, off, 64);
            sC += __shfl_down(sC, off, 64);
        }
        __shared__ double w1[4], wA[4], wC[4];
        int lane = tid & 63, w = tid >> 6;
        if (lane == 0) { w1[w] = s1; wA[w] = sA; wC[w] = sC; }
        __syncthreads();
        if (tid == 0) {
            double t1 = w1[0] + w1[1] + w1[2] + w1[3];
            double tA = wA[0] + wA[1] + wA[2] + wA[3];
            double tC = wC[0] + wC[1] + wC[2] + wC[3];
            if (t1 != 0.0) atomicAdd(&sums[1], t1);
            if (tA != 0.0) atomicAdd(&sums[0], tA);
            if (tC != 0.0) atomicAdd(&sums[2], tC);
        }
    }
}

// ---------------------------------------------------------------------------
// K3: combine (kernel boundary guarantees visibility of K2's atomics).
// ---------------------------------------------------------------------------
__global__ void finalK(const double* __restrict__ sums,
                       const int* __restrict__ counts,
                       float* __restrict__ out) {
    if (threadIdx.x == 0) {
        int npos = 0;
        for (int i = 0; i < BATCH; i++) npos += counts[i];
        double total = (sums[0] + 0.5 * sums[1]) / (double)TOT_CELLS;
        if (npos > 0) total += sums[2] / ((double)npos * (double)NC);
        out[0] = (float)total;
    }
}

extern "C" void kernel_launch(void* const* d_in, const int* in_sizes, int n_in,
                              void* d_out, int out_size, void* d_ws, size_t ws_size,
                              hipStream_t stream) {
    const float* pred = (const float*)d_in[0];   // (64, 10647, 85) f32
    const float* tgt  = (const float*)d_in[1];   // (64, 50, 5) f32
    // d_in[2] = stride (always 32; fsizes/last_num hardcoded)

    char* ws = (char*)d_ws;
    double* sums    = (double*)ws;                        // 4 doubles
    int*    counts  = (int*)(ws + 64);                    // 64 ints
    int*    hitcnt  = (int*)(ws + 320);                   // 64 ints
    int*    hitlist = (int*)(ws + 576);                   // 64*512 ints = 128 KiB
    Rec*    recs    = (Rec*)(ws + 576 + 131072);          // 64*64*40 = 160 KiB

    phaseA<<<BATCH, 64, 0, stream>>>(tgt, counts, recs, hitcnt, hitlist, sums);
    sumK<<<NB4 + BATCH, 256, 0, stream>>>(pred, counts, recs, hitcnt, hitlist, sums);
    finalK<<<1, 64, 0, stream>>>(sums, counts, (float*)d_out);
}

// Round 4
// 338.811 us; speedup vs baseline: 1.7484x; 1.0399x over previous
//
#include <hip/hip_runtime.h>
#include <math.h>

#define A_TOT   10647
#define BATCH   64
#define NTGT    50
#define NC      80
#define MAXHIT  512
#define TOT_CELLS (BATCH * A_TOT)          // 681408
#define NBD     666                        // ceil(681408/1024) dense blocks
#define GRID    (BATCH + NBD)              // 730 (sparse blocks first)

struct Rec {
    int cell;
    float tx, ty, tw, th, wwh, tconf;
    unsigned c0, c1, c2;     // 80-bit class set
};

// ---------------------------------------------------------------------------
// K1: one kernel, two block roles.
//   bid <  BATCH : "sparse" block — does full target matching for batch b in
//                  LDS (no global round-trip), then computes xywh MSE, masked
//                  conf BCE, hit-cell cancellation, and class BCE.
//   bid >= BATCH : "dense" block — sums -log(1-conf) over 1024 cells
//                  (4 independent loads/thread for latency hiding).
// Every block unconditionally writes its 3 partial doubles to its own slot —
// no zero-init, no atomics, no fences. finalK reduces the slots.
// ---------------------------------------------------------------------------
__global__ __launch_bounds__(256) void sumK(const float* __restrict__ pred,
                                            const float* __restrict__ tgt,
                                            double* __restrict__ part,
                                            int* __restrict__ counts) {
    const int bid = blockIdx.x;
    const int tid = threadIdx.x;
    double s1 = 0.0, sA = 0.0, sC = 0.0;

    if (bid >= BATCH) {
        // ---------------- dense role ----------------
        const int base = (bid - BATCH) * 1024 + tid;
        const int i0 = base, i1 = base + 256, i2 = base + 512, i3 = base + 768;
        float v0 = (i0 < TOT_CELLS) ? pred[(size_t)i0 * 85 + 4] : 0.0f;
        float v1 = (i1 < TOT_CELLS) ? pred[(size_t)i1 * 85 + 4] : 0.0f;
        float v2 = (i2 < TOT_CELLS) ? pred[(size_t)i2 * 85 + 4] : 0.0f;
        float v3 = (i3 < TOT_CELLS) ? pred[(size_t)i3 * 85 + 4] : 0.0f;
        s1 = -((double)logf(1.0f - v0) + (double)logf(1.0f - v1) +
               (double)logf(1.0f - v2) + (double)logf(1.0f - v3));
    } else {
        // ---------------- sparse role: batch b ----------------
        const int b = bid;
        __shared__ int   s_valid[NTGT];
        __shared__ int   s_idx[NTGT];
        __shared__ float s_tx[NTGT], s_ty[NTGT], s_tw[NTGT], s_th[NTGT];
        __shared__ float s_wwh[NTGT], s_tc[NTGT];
        __shared__ int   s_cls[NTGT];
        __shared__ Rec   s_rec[NTGT];
        __shared__ int   s_cnt;
        __shared__ unsigned s_bm[336];      // 10647-bit hit bitmap
        __shared__ int   s_hits[MAXHIT];
        __shared__ int   s_hc;

        for (int i = tid; i < 336; i += 256) s_bm[i] = 0u;
        if (tid == 0) s_hc = 0;
        __syncthreads();

        const float fs[3] = {13.f, 26.f, 52.f};
        const int   ln[3] = {0, 507, 2535};
        const float aw[3][3] = {{3.625f, 4.875f, 11.65625f},
                                {1.875f, 3.875f, 3.6875f},
                                {1.25f,  2.0f,   4.125f}};
        const float ah[3][3] = {{2.8125f, 6.1875f, 10.1875f},
                                {3.8125f, 2.8125f, 7.4375f},
                                {1.625f,  3.75f,   2.875f}};

        if (tid < NTGT) {
            const float* t = tgt + (size_t)(b * NTGT + tid) * 5;
            float t0 = t[0], t1 = t[1], t2 = t[2], t3 = t[3], t4 = t[4];
            int valid = ((t0 + t1 + t2 + t3 + t4) != 0.0f);
            s_valid[tid] = valid;
            if (valid) {
                float best_m_iou = -1.f;
                int bf = 0, best_a = 0, gi_b = 0, gj_b = 0;
                for (int m = 0; m < 3; m++) {
                    float gw = t3 * fs[m], gh = t4 * fs[m];
                    int gi = (int)floorf(t1 * fs[m]);
                    int gj = (int)floorf(t2 * fs[m]);
                    float bi = -1.f; int bk = 0;
                    for (int k = 0; k < 3; k++) {
                        float in_ = fminf(gw, aw[m][k]) * fminf(gh, ah[m][k]);
                        float un  = gw * gh + aw[m][k] * ah[m][k] - in_;
                        float iou = in_ / (un + 1e-16f);
                        if (iou > bi) { bi = iou; bk = k; }
                        if (iou > 0.5f) {                     // IGNORE_THR hit
                            int cell = ln[m] + 3 * gi * gj + k;
                            unsigned bit = 1u << (cell & 31);
                            unsigned old = atomicOr(&s_bm[cell >> 5], bit);
                            if (!(old & bit)) {
                                int pos = atomicAdd(&s_hc, 1);
                                s_hits[pos] = cell;
                            }
                        }
                    }
                    if (bi > best_m_iou) {
                        best_m_iou = bi; bf = m; best_a = bk; gi_b = gi; gj_b = gj;
                    }
                }
                s_idx[tid] = ln[bf] + 3 * gi_b * gj_b + best_a;
                s_tx[tid]  = t1 * 416.f;
                s_ty[tid]  = t2 * 416.f;
                s_tw[tid]  = t3 * 416.f;
                s_th[tid]  = t4 * 416.f;
                s_wwh[tid] = 2.0f - t3 * t4;
                s_tc[tid]  = best_m_iou;
                s_cls[tid] = (int)t0;
            }
        }
        __syncthreads();

        if (tid == 0) {
            // serial merge in n-order: last-write-wins matches numpy fancy
            // assignment; class bits union across targets in the same cell.
            int cnt = 0;
            for (int i = 0; i < NTGT; i++) {
                if (!s_valid[i]) continue;
                int cell = s_idx[i];
                int j = -1;
                for (int q = 0; q < cnt; q++)
                    if (s_rec[q].cell == cell) { j = q; break; }
                if (j < 0) {
                    j = cnt++;
                    s_rec[j].cell = cell;
                    s_rec[j].c0 = 0u; s_rec[j].c1 = 0u; s_rec[j].c2 = 0u;
                }
                s_rec[j].tx = s_tx[i];  s_rec[j].ty = s_ty[i];
                s_rec[j].tw = s_tw[i];  s_rec[j].th = s_th[i];
                s_rec[j].wwh = s_wwh[i]; s_rec[j].tconf = s_tc[i];
                int c = s_cls[i];
                if (c < 32)       s_rec[j].c0 |= 1u << c;
                else if (c < 64)  s_rec[j].c1 |= 1u << (c - 32);
                else              s_rec[j].c2 |= 1u << (c - 64);
            }
            s_cnt = cnt;
            counts[b] = cnt;
        }
        __syncthreads();
        const int cnt = s_cnt;
        const int hc  = s_hc;

        // cancel hit cells (they have noobj == 0 in the reference)
        for (int i = tid; i < hc; i += 256) {
            int cell = s_hits[i];
            float conf = pred[((size_t)b * A_TOT + cell) * 85 + 4];
            s1 += (double)logf(1.0f - conf);
        }
        // masked-cell terms: xywh MSE + conf BCE
        for (int r = tid; r < cnt; r += 256) {
            Rec rec = s_rec[r];
            const float* p = pred + ((size_t)b * A_TOT + rec.cell) * 85;
            float x = p[0], y = p[1], w = p[2], h = p[3], conf = p[4];
            float wwh = rec.wwh;
            float dx = x * wwh - rec.tx * wwh;
            float dy = y * wwh - rec.ty * wwh;
            float dw = w * wwh - rec.tw * wwh;
            float dh = h * wwh - rec.th * wwh;
            sA += (double)(dx * dx) + (double)(dy * dy) +
                  (double)(dw * dw) + (double)(dh * dh);
            float t = rec.tconf;
            sA -= (double)(t * logf(conf) + (1.0f - t) * logf(1.0f - conf));
        }
        // class BCE over cnt*80 elements
        for (int q = tid; q < cnt * NC; q += 256) {
            int r = q / NC, c = q - r * NC;
            Rec rec = s_rec[r];
            float pc = pred[((size_t)b * A_TOT + rec.cell) * 85 + 5 + c];
            unsigned bit;
            if (c < 32)       bit = (rec.c0 >> c) & 1u;
            else if (c < 64)  bit = (rec.c1 >> (c - 32)) & 1u;
            else              bit = (rec.c2 >> (c - 64)) & 1u;
            sC -= bit ? (double)logf(pc) : (double)logf(1.0f - pc);
        }
    }

    // block reduction (wave64 shuffle + LDS across 4 waves), then one
    // unconditional slot write per block — no atomics, no init required.
    for (int off = 32; off; off >>= 1) {
        s1 += __shfl_down(s1, off, 64);
        sA += __shfl_down(sA, off, 64);
        sC += __shfl_down(sC, off, 64);
    }
    __shared__ double w1[4], wA[4], wC[4];
    int lane = tid & 63, w = tid >> 6;
    if (lane == 0) { w1[w] = s1; wA[w] = sA; wC[w] = sC; }
    __syncthreads();
    if (tid == 0) {
        part[bid * 3 + 0] = w1[0] + w1[1] + w1[2] + w1[3];
        part[bid * 3 + 1] = wA[0] + wA[1] + wA[2] + wA[3];
        part[bid * 3 + 2] = wC[0] + wC[1] + wC[2] + wC[3];
    }
}

// ---------------------------------------------------------------------------
// K2: reduce the 730 partial slots + 64 counts, combine.
// ---------------------------------------------------------------------------
__global__ __launch_bounds__(256) void finalK(const double* __restrict__ part,
                                              const int* __restrict__ counts,
                                              float* __restrict__ out) {
    const int tid = threadIdx.x;
    double s1 = 0.0, sA = 0.0, sC = 0.0;
    for (int i = tid; i < GRID; i += 256) {
        s1 += part[i * 3 + 0];
        sA += part[i * 3 + 1];
        sC += part[i * 3 + 2];
    }
    int np = (tid < BATCH) ? counts[tid] : 0;
    for (int off = 32; off; off >>= 1) {
        s1 += __shfl_down(s1, off, 64);
        sA += __shfl_down(sA, off, 64);
        sC += __shfl_down(sC, off, 64);
        np += __shfl_down(np, off, 64);
    }
    __shared__ double w1[4], wA[4], wC[4];
    __shared__ int    wN[4];
    int lane = tid & 63, w = tid >> 6;
    if (lane == 0) { w1[w] = s1; wA[w] = sA; wC[w] = sC; wN[w] = np; }
    __syncthreads();
    if (tid == 0) {
        double f1 = w1[0] + w1[1] + w1[2] + w1[3];
        double fA = wA[0] + wA[1] + wA[2] + wA[3];
        double fC = wC[0] + wC[1] + wC[2] + wC[3];
        int npos  = wN[0] + wN[1] + wN[2] + wN[3];
        double total = (fA + 0.5 * f1) / (double)TOT_CELLS;
        if (npos > 0) total += fC / ((double)npos * (double)NC);
        out[0] = (float)total;
    }
}

extern "C" void kernel_launch(void* const* d_in, const int* in_sizes, int n_in,
                              void* d_out, int out_size, void* d_ws, size_t ws_size,
                              hipStream_t stream) {
    const float* pred = (const float*)d_in[0];   // (64, 10647, 85) f32
    const float* tgt  = (const float*)d_in[1];   // (64, 50, 5) f32
    // d_in[2] = stride (always 32; fsizes/last_num hardcoded)

    char* ws = (char*)d_ws;
    double* part   = (double*)ws;                 // GRID*3 doubles = 17.5 KB
    int*    counts = (int*)(ws + 32768);          // 64 ints

    sumK<<<GRID, 256, 0, stream>>>(pred, tgt, part, counts);
    finalK<<<1, 256, 0, stream>>>(part, counts, (float*)d_out);
}